// Round 8
// baseline (77.960 us; speedup 1.0000x reference)
//
#include <hip/hip_runtime.h>

#define BB 16
#define QQ 64
#define KK 512
#define DD 256
#define HH 256
#define KTILE 128
#define NZ 4

#define LOG2E2 2.88539008177792681f   // 2*log2(e): exp2(LOG2E2*x) = e^{2x}

typedef unsigned int uint;
typedef unsigned short ushort;

__device__ __forceinline__ float fast_exp2(float x) {
#if __has_builtin(__builtin_amdgcn_exp2f)
    return __builtin_amdgcn_exp2f(x);
#else
    return exp2f(x);
#endif
}

__device__ __forceinline__ ushort f32_to_bf16_rtne(float x) {
    uint u = __float_as_uint(x);
    u = (u + 0x7FFFu + ((u >> 16) & 1u)) >> 16;
    return (ushort)u;
}

// unpack 8 bf16 (uint4) -> two float4
__device__ __forceinline__ void cvt8(uint4 u, float4& a, float4& b) {
    a.x = __uint_as_float(u.x << 16); a.y = __uint_as_float(u.x & 0xFFFF0000u);
    a.z = __uint_as_float(u.y << 16); a.w = __uint_as_float(u.y & 0xFFFF0000u);
    b.x = __uint_as_float(u.z << 16); b.y = __uint_as_float(u.z & 0xFFFF0000u);
    b.z = __uint_as_float(u.w << 16); b.w = __uint_as_float(u.w & 0xFFFF0000u);
}

// ---------------------------------------------------------------------------
// Both projections, one launch. q-features -> f32 (1MB); k-features -> bf16
// (4MB). Both pre-scaled by 2log2e. Fully-masked key tiles skipped.
// ---------------------------------------------------------------------------
__global__ __launch_bounds__(256) void proj_both(
        const float* __restrict__ Xq, const float* __restrict__ Wq, float* __restrict__ Yq,
        const float* __restrict__ Xk, const float* __restrict__ Wk, ushort* __restrict__ Yk16,
        const int* __restrict__ valid_lens) {
    __shared__ float XsT[32][68];
    __shared__ float Ws[32][64];
    const int rt = blockIdx.x;
    const bool is_q = (rt < 16);
    const float* X; const float* W; int row0;
    if (is_q) { X = Xq; W = Wq; row0 = rt * 64; }
    else {
        X = Xk; W = Wk; row0 = (rt - 16) * 64;
        const int bb    = row0 >> 9;
        const int local = row0 & 511;
        if (local >= valid_lens[bb]) return;
    }
    const int col0 = blockIdx.y * 64;
    const int tid = threadIdx.x;
    const int tx = tid & 15, ty = tid >> 4;

    float acc[4][4] = {};

    for (int k0 = 0; k0 < HH; k0 += 32) {
        {
            const int m  = tid >> 3;
            const int kk = (tid & 7) * 4;
            #pragma unroll
            for (int s = 0; s < 2; ++s) {
                float4 x4 = *(const float4*)(X + (size_t)(row0 + m + 32*s) * HH + k0 + kk);
                XsT[kk+0][m+32*s] = x4.x;
                XsT[kk+1][m+32*s] = x4.y;
                XsT[kk+2][m+32*s] = x4.z;
                XsT[kk+3][m+32*s] = x4.w;
            }
        }
        {
            const int kk = tid >> 4;
            const int c  = (tid & 15) * 4;
            #pragma unroll
            for (int s = 0; s < 2; ++s) {
                float4 w4 = *(const float4*)(W + (size_t)(k0 + kk + 16*s) * HH + col0 + c);
                *(float4*)(&Ws[kk+16*s][c]) = w4;
            }
        }
        __syncthreads();
        #pragma unroll
        for (int kk = 0; kk < 32; ++kk) {
            float4 a = *(const float4*)(&XsT[kk][ty*4]);
            float4 b = *(const float4*)(&Ws[kk][tx*4]);
            acc[0][0] += a.x*b.x; acc[0][1] += a.x*b.y; acc[0][2] += a.x*b.z; acc[0][3] += a.x*b.w;
            acc[1][0] += a.y*b.x; acc[1][1] += a.y*b.y; acc[1][2] += a.y*b.z; acc[1][3] += a.y*b.w;
            acc[2][0] += a.z*b.x; acc[2][1] += a.z*b.y; acc[2][2] += a.z*b.z; acc[2][3] += a.z*b.w;
            acc[3][0] += a.w*b.x; acc[3][1] += a.w*b.y; acc[3][2] += a.w*b.z; acc[3][3] += a.w*b.w;
        }
        __syncthreads();
    }
    if (is_q) {
        float* Y = (float*)Yq;
        #pragma unroll
        for (int i = 0; i < 4; ++i) {
            float4 o = make_float4(acc[i][0]*LOG2E2, acc[i][1]*LOG2E2,
                                   acc[i][2]*LOG2E2, acc[i][3]*LOG2E2);
            *(float4*)(Y + (size_t)(row0 + ty*4 + i) * HH + col0 + tx*4) = o;
        }
    } else {
        #pragma unroll
        for (int i = 0; i < 4; ++i) {
            ushort4 o;
            o.x = f32_to_bf16_rtne(acc[i][0]*LOG2E2);
            o.y = f32_to_bf16_rtne(acc[i][1]*LOG2E2);
            o.z = f32_to_bf16_rtne(acc[i][2]*LOG2E2);
            o.w = f32_to_bf16_rtne(acc[i][3]*LOG2E2);
            *(ushort4*)(Yk16 + (size_t)(row0 + ty*4 + i) * HH + col0 + tx*4) = o;
        }
    }
}

// ---------------------------------------------------------------------------
// Flash-style fused tile kernel. 1D grid of BB*QQ*NZ uniform quanta, XCD-
// swizzled. Block (b,q,z): key tile [z*128, min(z*128+128, vl)); exits if
// fully masked. Computes tile scores (LDS), tile max m_z / sum l_z,
// unnormalized p, PV partial o_z -> workspace. 256 thr, 4 waves.
// ---------------------------------------------------------------------------
__global__ __launch_bounds__(256) void fused_flash(
        const float* __restrict__ qf, const ushort* __restrict__ kf16,
        const float* __restrict__ w_v, const int* __restrict__ valid_lens,
        const float* __restrict__ values,
        float* __restrict__ pm, float* __restrict__ pl, float* __restrict__ po) {
    // bijective XCD swizzle: 4096 blocks, 8 XCDs, 512 per XCD chunk
    const int orig = blockIdx.x;
    const int wgid = (orig & 7) * 512 + (orig >> 3);
    const int b = wgid >> 8;
    const int q = (wgid & 255) >> 2;
    const int z = wgid & 3;

    const int vl      = valid_lens[b];
    const int tile_lo = z * KTILE;
    if (tile_lo >= vl) return;
    const int tile_hi = (tile_lo + KTILE < vl) ? (tile_lo + KTILE) : vl;
    const int tcnt    = tile_hi - tile_lo;

    __shared__ float sc[KTILE];     // tile scores -> p
    __shared__ float red[4][DD];    // PV partials
    const int tid  = threadIdx.x;
    const int lane = tid & 63;
    const int w    = tid >> 6;
    const int hg   = lane & 15;
    const int ksub = lane >> 4;
    const int h0   = hg * 16;

    if (tid < KTILE) sc[tid] = -1e6f;

    float4 nw[4];
    float wvsum = 0.f;
    #pragma unroll
    for (int i = 0; i < 4; ++i) {
        float4 wv4 = *(const float4*)(w_v + h0 + i*4);
        wvsum += ((wv4.x + wv4.y) + (wv4.z + wv4.w));
        nw[i] = make_float4(-2.f*wv4.x, -2.f*wv4.y, -2.f*wv4.z, -2.f*wv4.w);
    }
    float4 qv[4];
    {
        const float* qr = qf + (size_t)(b*QQ + q) * HH + h0;
        #pragma unroll
        for (int i = 0; i < 4; ++i) qv[i] = *(const float4*)(qr + i*4);
    }

    // balanced strip within tile for this wave
    const int rpw = (tcnt + 3) >> 2;
    const int lo  = tile_lo + w * rpw;
    int hi = lo + rpw; hi = (hi > tile_hi) ? tile_hi : hi;
    const int cnt = hi - lo;
    const int ng  = (cnt <= 0) ? 0 : ((cnt + 3) >> 2);

    __syncthreads();   // sc init visible

    // ---- Phase A: tile scores ----
    {
        const size_t brows = (size_t)b * KK;
        auto rowptr = [&](int g) -> const ushort* {
            int row = lo + g*4 + ksub;
            row = (row < tile_hi) ? row : (tile_hi - 1);   // stay in valid rows
            return kf16 + (brows + row) * HH + h0;
        };
        uint4 c0, c1;
        if (ng > 0) {
            const ushort* p = rowptr(0);
            c0 = *(const uint4*)(p);
            c1 = *(const uint4*)(p + 8);
        }
        for (int g = 0; g < ng; ++g) {
            uint4 n0, n1;
            const bool more = (g + 1 < ng);
            if (more) {
                const ushort* p = rowptr(g + 1);
                n0 = *(const uint4*)(p);
                n1 = *(const uint4*)(p + 8);
            }
            float4 kv[4];
            cvt8(c0, kv[0], kv[1]);
            cvt8(c1, kv[2], kv[3]);

            float a0 = wvsum, a1 = 0.f, a2 = 0.f, a3 = 0.f;
            #pragma unroll
            for (int i = 0; i < 4; ++i) {
                float e0 = fast_exp2(qv[i].x + kv[i].x);
                float e1 = fast_exp2(qv[i].y + kv[i].y);
                float e2 = fast_exp2(qv[i].z + kv[i].z);
                float e3 = fast_exp2(qv[i].w + kv[i].w);
                a0 = fmaf(nw[i].x, __builtin_amdgcn_rcpf(e0 + 1.f), a0);
                a1 = fmaf(nw[i].y, __builtin_amdgcn_rcpf(e1 + 1.f), a1);
                a2 = fmaf(nw[i].z, __builtin_amdgcn_rcpf(e2 + 1.f), a2);
                a3 = fmaf(nw[i].w, __builtin_amdgcn_rcpf(e3 + 1.f), a3);
            }
            float s = (a0 + a1) + (a2 + a3);
            s += __shfl_xor(s, 8);
            s += __shfl_xor(s, 4);
            s += __shfl_xor(s, 2);
            s += __shfl_xor(s, 1);

            const int k = lo + g*4 + ksub;
            if (hg == 0 && k < hi) sc[k - tile_lo] = s;

            if (more) { c0 = n0; c1 = n1; }
        }
    }
    __syncthreads();

    // ---- Phase B: tile max/sum + unnormalized p (each wave redundantly) ----
    float m, l;
    {
        float s0 = sc[lane*2], s1 = sc[lane*2 + 1];
        m = fmaxf(s0, s1);
        #pragma unroll
        for (int off = 32; off; off >>= 1) m = fmaxf(m, __shfl_xor(m, off));
        float p0 = __expf(s0 - m), p1 = __expf(s1 - m);
        l = p0 + p1;
        #pragma unroll
        for (int off = 32; off; off >>= 1) l += __shfl_xor(l, off);
        if ((lane >> 4) == w) {    // each wave stores its quarter (identical values)
            sc[lane*2]     = p0;
            sc[lane*2 + 1] = p1;
        }
    }
    const int idx = ((b*QQ + q) << 2) + z;
    if (tid == 0) { pm[idx] = m; pl[idx] = l; }
    __syncthreads();

    // ---- Phase C: PV partial over the same strip ----
    {
        const float* V = values + (size_t)b * KK * DD + lane*4;
        float4 a0 = make_float4(0.f,0.f,0.f,0.f), a1 = a0, a2 = a0, a3 = a0;
        int k = lo;
        for (; k + 4 <= hi; k += 4) {
            const float p0 = sc[k   - tile_lo], p1 = sc[k+1 - tile_lo];
            const float p2 = sc[k+2 - tile_lo], p3 = sc[k+3 - tile_lo];
            float4 v0 = *(const float4*)(V + (size_t)(k+0) * DD);
            float4 v1 = *(const float4*)(V + (size_t)(k+1) * DD);
            float4 v2 = *(const float4*)(V + (size_t)(k+2) * DD);
            float4 v3 = *(const float4*)(V + (size_t)(k+3) * DD);
            a0.x += p0*v0.x; a0.y += p0*v0.y; a0.z += p0*v0.z; a0.w += p0*v0.w;
            a1.x += p1*v1.x; a1.y += p1*v1.y; a1.z += p1*v1.z; a1.w += p1*v1.w;
            a2.x += p2*v2.x; a2.y += p2*v2.y; a2.z += p2*v2.z; a2.w += p2*v2.w;
            a3.x += p3*v3.x; a3.y += p3*v3.y; a3.z += p3*v3.z; a3.w += p3*v3.w;
        }
        for (; k < hi; ++k) {
            const float pw = sc[k - tile_lo];
            float4 v4 = *(const float4*)(V + (size_t)k * DD);
            a0.x += pw*v4.x; a0.y += pw*v4.y; a0.z += pw*v4.z; a0.w += pw*v4.w;
        }
        float4 acc;
        acc.x = (a0.x + a1.x) + (a2.x + a3.x);
        acc.y = (a0.y + a1.y) + (a2.y + a3.y);
        acc.z = (a0.z + a1.z) + (a2.z + a3.z);
        acc.w = (a0.w + a1.w) + (a2.w + a3.w);
        *(float4*)(&red[w][lane*4]) = acc;
    }
    __syncthreads();

    po[(size_t)idx * DD + tid] =
        (red[0][tid] + red[1][tid]) + (red[2][tid] + red[3][tid]);
}

// ---------------------------------------------------------------------------
// Combine <=4 tile partials per (b,q): online-softmax merge. grid (B,Q), 256.
// ---------------------------------------------------------------------------
__global__ __launch_bounds__(256) void combine_kernel(
        const float* __restrict__ pm, const float* __restrict__ pl,
        const float* __restrict__ po, const int* __restrict__ valid_lens,
        float* __restrict__ out) {
    const int b   = blockIdx.x;
    const int q   = blockIdx.y;
    const int tid = threadIdx.x;
    const int vl  = valid_lens[b];
    const int nz  = (vl + KTILE - 1) >> 7;
    const int idx4 = (b*QQ + q) << 2;

    float mz[NZ], wz[NZ];
    float M = -3.0e38f;
    #pragma unroll
    for (int z = 0; z < NZ; ++z) {
        mz[z] = (z < nz) ? pm[idx4 + z] : -3.0e38f;
        M = fmaxf(M, mz[z]);
    }
    float L = 0.f;
    #pragma unroll
    for (int z = 0; z < NZ; ++z) {
        wz[z] = (z < nz) ? __expf(mz[z] - M) : 0.f;
        L = fmaf(wz[z], (z < nz) ? pl[idx4 + z] : 0.f, L);
    }
    const float inv = 1.f / L;

    float o = 0.f;
    #pragma unroll
    for (int z = 0; z < NZ; ++z) {
        if (z < nz)
            o = fmaf(wz[z], po[(size_t)(idx4 + z) * DD + tid], o);
    }
    out[(size_t)(b*QQ + q) * DD + tid] = o * inv;
}

extern "C" void kernel_launch(void* const* d_in, const int* in_sizes, int n_in,
                              void* d_out, int out_size, void* d_ws, size_t ws_size,
                              hipStream_t stream) {
    (void)in_sizes; (void)n_in; (void)out_size; (void)ws_size;
    const float* querys     = (const float*)d_in[0];
    const float* keys       = (const float*)d_in[1];
    const float* values     = (const float*)d_in[2];
    const int*   valid_lens = (const int*)d_in[3];
    const float* Wq         = (const float*)d_in[4];
    const float* Wk         = (const float*)d_in[5];
    const float* w_v        = (const float*)d_in[6];
    float* out = (float*)d_out;

    float*  qf    = (float*)d_ws;                          // 1 MB f32 (pre-scaled)
    ushort* kfeat = (ushort*)(qf + (size_t)BB*QQ*HH);      // 4 MB bf16 (pre-scaled)
    float*  pm    = (float*)(kfeat + (size_t)BB*KK*HH);    // 16 KB
    float*  pl    = pm + BB*QQ*NZ;                         // 16 KB
    float*  po    = pl + BB*QQ*NZ;                         // 4 MB

    proj_both<<<dim3(16 + BB*KK/64, HH/64), 256, 0, stream>>>(
        querys, Wq, qf, keys, Wk, kfeat, valid_lens);
    fused_flash<<<dim3(BB*QQ*NZ), 256, 0, stream>>>(
        qf, kfeat, w_v, valid_lens, values, pm, pl, po);
    combine_kernel<<<dim3(BB, QQ), 256, 0, stream>>>(
        pm, pl, po, valid_lens, out);
}

// Round 9
// 60.498 us; speedup vs baseline: 1.2886x; 1.2886x over previous
//
#include <hip/hip_runtime.h>

#define BB 16
#define QQ 64
#define KK 512
#define DD 256
#define HH 256
#define KTILE 128
#define NZ 4
#define PERSIST 2048

#define LOG2E2 2.88539008177792681f   // 2*log2(e): exp2(LOG2E2*x) = e^{2x}

typedef unsigned int uint;
typedef unsigned short ushort;

__device__ __forceinline__ float fast_exp2(float x) {
#if __has_builtin(__builtin_amdgcn_exp2f)
    return __builtin_amdgcn_exp2f(x);
#else
    return exp2f(x);
#endif
}

__device__ __forceinline__ ushort f32_to_bf16_rtne(float x) {
    uint u = __float_as_uint(x);
    u = (u + 0x7FFFu + ((u >> 16) & 1u)) >> 16;
    return (ushort)u;
}

// unpack 8 bf16 (uint4) -> two float4
__device__ __forceinline__ void cvt8(uint4 u, float4& a, float4& b) {
    a.x = __uint_as_float(u.x << 16); a.y = __uint_as_float(u.x & 0xFFFF0000u);
    a.z = __uint_as_float(u.y << 16); a.w = __uint_as_float(u.y & 0xFFFF0000u);
    b.x = __uint_as_float(u.z << 16); b.y = __uint_as_float(u.z & 0xFFFF0000u);
    b.z = __uint_as_float(u.w << 16); b.w = __uint_as_float(u.w & 0xFFFF0000u);
}

// ---------------------------------------------------------------------------
// Both projections, one launch. q-features -> f32 (1MB); k-features -> bf16
// (4MB). Both pre-scaled by 2log2e. Fully-masked key tiles skipped.
// ---------------------------------------------------------------------------
__global__ __launch_bounds__(256) void proj_both(
        const float* __restrict__ Xq, const float* __restrict__ Wq, float* __restrict__ Yq,
        const float* __restrict__ Xk, const float* __restrict__ Wk, ushort* __restrict__ Yk16,
        const int* __restrict__ valid_lens) {
    __shared__ float XsT[32][68];
    __shared__ float Ws[32][64];
    const int rt = blockIdx.x;
    const bool is_q = (rt < 16);
    const float* X; const float* W; int row0;
    if (is_q) { X = Xq; W = Wq; row0 = rt * 64; }
    else {
        X = Xk; W = Wk; row0 = (rt - 16) * 64;
        const int bb    = row0 >> 9;
        const int local = row0 & 511;
        if (local >= valid_lens[bb]) return;
    }
    const int col0 = blockIdx.y * 64;
    const int tid = threadIdx.x;
    const int tx = tid & 15, ty = tid >> 4;

    float acc[4][4] = {};

    for (int k0 = 0; k0 < HH; k0 += 32) {
        {
            const int m  = tid >> 3;
            const int kk = (tid & 7) * 4;
            #pragma unroll
            for (int s = 0; s < 2; ++s) {
                float4 x4 = *(const float4*)(X + (size_t)(row0 + m + 32*s) * HH + k0 + kk);
                XsT[kk+0][m+32*s] = x4.x;
                XsT[kk+1][m+32*s] = x4.y;
                XsT[kk+2][m+32*s] = x4.z;
                XsT[kk+3][m+32*s] = x4.w;
            }
        }
        {
            const int kk = tid >> 4;
            const int c  = (tid & 15) * 4;
            #pragma unroll
            for (int s = 0; s < 2; ++s) {
                float4 w4 = *(const float4*)(W + (size_t)(k0 + kk + 16*s) * HH + col0 + c);
                *(float4*)(&Ws[kk+16*s][c]) = w4;
            }
        }
        __syncthreads();
        #pragma unroll
        for (int kk = 0; kk < 32; ++kk) {
            float4 a = *(const float4*)(&XsT[kk][ty*4]);
            float4 b = *(const float4*)(&Ws[kk][tx*4]);
            acc[0][0] += a.x*b.x; acc[0][1] += a.x*b.y; acc[0][2] += a.x*b.z; acc[0][3] += a.x*b.w;
            acc[1][0] += a.y*b.x; acc[1][1] += a.y*b.y; acc[1][2] += a.y*b.z; acc[1][3] += a.y*b.w;
            acc[2][0] += a.z*b.x; acc[2][1] += a.z*b.y; acc[2][2] += a.z*b.z; acc[2][3] += a.z*b.w;
            acc[3][0] += a.w*b.x; acc[3][1] += a.w*b.y; acc[3][2] += a.w*b.z; acc[3][3] += a.w*b.w;
        }
        __syncthreads();
    }
    if (is_q) {
        float* Y = (float*)Yq;
        #pragma unroll
        for (int i = 0; i < 4; ++i) {
            float4 o = make_float4(acc[i][0]*LOG2E2, acc[i][1]*LOG2E2,
                                   acc[i][2]*LOG2E2, acc[i][3]*LOG2E2);
            *(float4*)(Y + (size_t)(row0 + ty*4 + i) * HH + col0 + tx*4) = o;
        }
    } else {
        #pragma unroll
        for (int i = 0; i < 4; ++i) {
            ushort4 o;
            o.x = f32_to_bf16_rtne(acc[i][0]*LOG2E2);
            o.y = f32_to_bf16_rtne(acc[i][1]*LOG2E2);
            o.z = f32_to_bf16_rtne(acc[i][2]*LOG2E2);
            o.w = f32_to_bf16_rtne(acc[i][3]*LOG2E2);
            *(ushort4*)(Yk16 + (size_t)(row0 + ty*4 + i) * HH + col0 + tx*4) = o;
        }
    }
}

// ---------------------------------------------------------------------------
// Persistent flash-style fused kernel. Grid = 2048 blocks (8/CU pinned).
// Work items = (active tile (b,z)) x 64 q, enumerated via prefix scan of
// ceil(vl/128) over the 16 batches; block bid processes items bid,
// bid+2048, ... Every launched block gets ceil(T/2048) items -> no drain
// tail, 32 waves/CU resident throughout. Per item: tile scores -> LDS,
// tile max/sum, unnormalized p (separate pp buffer, no race), PV partial.
// ---------------------------------------------------------------------------
__global__ __launch_bounds__(256) void fused_flash(
        const float* __restrict__ qf, const ushort* __restrict__ kf16,
        const float* __restrict__ w_v, const int* __restrict__ valid_lens,
        const float* __restrict__ values,
        float* __restrict__ pm, float* __restrict__ pl, float* __restrict__ po) {
    __shared__ float sc[KTILE];     // tile scores (-1e6 = masked)
    __shared__ float pp[KTILE];     // unnormalized probs
    __shared__ float red[4][DD];    // PV partials

    const int tid  = threadIdx.x;
    const int lane = tid & 63;
    const int w    = tid >> 6;
    const int hg   = lane & 15;
    const int ksub = lane >> 4;
    const int h0   = hg * 16;

    float4 nw[4];
    float wvsum = 0.f;
    #pragma unroll
    for (int i = 0; i < 4; ++i) {
        float4 wv4 = *(const float4*)(w_v + h0 + i*4);
        wvsum += ((wv4.x + wv4.y) + (wv4.z + wv4.w));
        nw[i] = make_float4(-2.f*wv4.x, -2.f*wv4.y, -2.f*wv4.z, -2.f*wv4.w);
    }

    // total active tiles
    int TT = 0;
    #pragma unroll
    for (int i = 0; i < BB; ++i)
        TT += (valid_lens[i] + KTILE - 1) >> 7;
    const int items = TT * QQ;

    for (int t = blockIdx.x; t < items; t += PERSIST) {
        const int tile_idx = t >> 6;
        const int q        = t & 63;

        // map tile_idx -> (b, z) via unrolled prefix scan
        int bb = 0, zz = 0, vlb = 1, acc = 0;
        #pragma unroll
        for (int i = 0; i < BB; ++i) {
            const int v   = valid_lens[i];
            const int nzi = (v + KTILE - 1) >> 7;
            const bool hit = (tile_idx >= acc) && (tile_idx < acc + nzi);
            if (hit) { bb = i; zz = tile_idx - acc; vlb = v; }
            acc += nzi;
        }

        const int tile_lo = zz * KTILE;
        const int tile_hi = (tile_lo + KTILE < vlb) ? (tile_lo + KTILE) : vlb;
        const int tcnt    = tile_hi - tile_lo;

        if (tid < KTILE) sc[tid] = -1e6f;

        float4 qv[4];
        {
            const float* qr = qf + (size_t)(bb*QQ + q) * HH + h0;
            #pragma unroll
            for (int i = 0; i < 4; ++i) qv[i] = *(const float4*)(qr + i*4);
        }

        // balanced strip within tile for this wave
        const int rpw = (tcnt + 3) >> 2;
        const int lo  = tile_lo + w * rpw;
        int hi = lo + rpw; hi = (hi > tile_hi) ? tile_hi : hi;
        const int cnt = hi - lo;
        const int ng  = (cnt <= 0) ? 0 : ((cnt + 3) >> 2);

        __syncthreads();   // sc init visible; prev item fully consumed

        // ---- Phase A: tile scores ----
        {
            const size_t brows = (size_t)bb * KK;
            uint4 c0, c1;
            {
                int row = lo + ksub;
                row = (row < tile_hi) ? row : (tile_hi - 1);
                const ushort* p = kf16 + (brows + row) * HH + h0;
                if (ng > 0) { c0 = *(const uint4*)(p); c1 = *(const uint4*)(p + 8); }
            }
            for (int g = 0; g < ng; ++g) {
                uint4 n0, n1;
                const bool more = (g + 1 < ng);
                if (more) {
                    int row = lo + (g+1)*4 + ksub;
                    row = (row < tile_hi) ? row : (tile_hi - 1);
                    const ushort* p = kf16 + (brows + row) * HH + h0;
                    n0 = *(const uint4*)(p);
                    n1 = *(const uint4*)(p + 8);
                }
                float4 kv[4];
                cvt8(c0, kv[0], kv[1]);
                cvt8(c1, kv[2], kv[3]);

                float a0 = wvsum, a1 = 0.f, a2 = 0.f, a3 = 0.f;
                #pragma unroll
                for (int i = 0; i < 4; ++i) {
                    float e0 = fast_exp2(qv[i].x + kv[i].x);
                    float e1 = fast_exp2(qv[i].y + kv[i].y);
                    float e2 = fast_exp2(qv[i].z + kv[i].z);
                    float e3 = fast_exp2(qv[i].w + kv[i].w);
                    a0 = fmaf(nw[i].x, __builtin_amdgcn_rcpf(e0 + 1.f), a0);
                    a1 = fmaf(nw[i].y, __builtin_amdgcn_rcpf(e1 + 1.f), a1);
                    a2 = fmaf(nw[i].z, __builtin_amdgcn_rcpf(e2 + 1.f), a2);
                    a3 = fmaf(nw[i].w, __builtin_amdgcn_rcpf(e3 + 1.f), a3);
                }
                float s = (a0 + a1) + (a2 + a3);
                s += __shfl_xor(s, 8);
                s += __shfl_xor(s, 4);
                s += __shfl_xor(s, 2);
                s += __shfl_xor(s, 1);

                const int k = lo + g*4 + ksub;
                if (hg == 0 && k < hi) sc[k - tile_lo] = s;

                if (more) { c0 = n0; c1 = n1; }
            }
        }
        __syncthreads();

        // ---- Phase B: tile max/sum + unnormalized p (redundant per wave) ----
        const int idx = ((bb*QQ + q) << 2) + zz;
        {
            float s0 = sc[lane*2], s1 = sc[lane*2 + 1];
            float m = fmaxf(s0, s1);
            #pragma unroll
            for (int off = 32; off; off >>= 1) m = fmaxf(m, __shfl_xor(m, off));
            float p0 = __expf(s0 - m), p1 = __expf(s1 - m);
            float l = p0 + p1;
            #pragma unroll
            for (int off = 32; off; off >>= 1) l += __shfl_xor(l, off);
            if (w == 0) {                 // one wave writes; values identical
                pp[lane*2]     = p0;
                pp[lane*2 + 1] = p1;
            }
            if (tid == 0) { pm[idx] = m; pl[idx] = l; }
        }
        __syncthreads();

        // ---- Phase C: PV partial over the same strip ----
        {
            const float* V = values + (size_t)bb * KK * DD + lane*4;
            float4 a0 = make_float4(0.f,0.f,0.f,0.f), a1 = a0, a2 = a0, a3 = a0;
            int k = lo;
            for (; k + 4 <= hi; k += 4) {
                const float p0 = pp[k   - tile_lo], p1 = pp[k+1 - tile_lo];
                const float p2 = pp[k+2 - tile_lo], p3 = pp[k+3 - tile_lo];
                float4 v0 = *(const float4*)(V + (size_t)(k+0) * DD);
                float4 v1 = *(const float4*)(V + (size_t)(k+1) * DD);
                float4 v2 = *(const float4*)(V + (size_t)(k+2) * DD);
                float4 v3 = *(const float4*)(V + (size_t)(k+3) * DD);
                a0.x += p0*v0.x; a0.y += p0*v0.y; a0.z += p0*v0.z; a0.w += p0*v0.w;
                a1.x += p1*v1.x; a1.y += p1*v1.y; a1.z += p1*v1.z; a1.w += p1*v1.w;
                a2.x += p2*v2.x; a2.y += p2*v2.y; a2.z += p2*v2.z; a2.w += p2*v2.w;
                a3.x += p3*v3.x; a3.y += p3*v3.y; a3.z += p3*v3.z; a3.w += p3*v3.w;
            }
            for (; k < hi; ++k) {
                const float pw = pp[k - tile_lo];
                float4 v4 = *(const float4*)(V + (size_t)k * DD);
                a0.x += pw*v4.x; a0.y += pw*v4.y; a0.z += pw*v4.z; a0.w += pw*v4.w;
            }
            float4 acc4;
            acc4.x = (a0.x + a1.x) + (a2.x + a3.x);
            acc4.y = (a0.y + a1.y) + (a2.y + a3.y);
            acc4.z = (a0.z + a1.z) + (a2.z + a3.z);
            acc4.w = (a0.w + a1.w) + (a2.w + a3.w);
            *(float4*)(&red[w][lane*4]) = acc4;
        }
        __syncthreads();

        po[(size_t)idx * DD + tid] =
            (red[0][tid] + red[1][tid]) + (red[2][tid] + red[3][tid]);
    }
}

// ---------------------------------------------------------------------------
// Combine <=4 tile partials per (b,q): online-softmax merge. grid (B,Q), 256.
// ---------------------------------------------------------------------------
__global__ __launch_bounds__(256) void combine_kernel(
        const float* __restrict__ pm, const float* __restrict__ pl,
        const float* __restrict__ po, const int* __restrict__ valid_lens,
        float* __restrict__ out) {
    const int b   = blockIdx.x;
    const int q   = blockIdx.y;
    const int tid = threadIdx.x;
    const int vl  = valid_lens[b];
    const int nz  = (vl + KTILE - 1) >> 7;
    const int idx4 = (b*QQ + q) << 2;

    float mz[NZ], wz[NZ];
    float M = -3.0e38f;
    #pragma unroll
    for (int z = 0; z < NZ; ++z) {
        mz[z] = (z < nz) ? pm[idx4 + z] : -3.0e38f;
        M = fmaxf(M, mz[z]);
    }
    float L = 0.f;
    #pragma unroll
    for (int z = 0; z < NZ; ++z) {
        wz[z] = (z < nz) ? __expf(mz[z] - M) : 0.f;
        L = fmaf(wz[z], (z < nz) ? pl[idx4 + z] : 0.f, L);
    }
    const float inv = 1.f / L;

    float o = 0.f;
    #pragma unroll
    for (int z = 0; z < NZ; ++z) {
        if (z < nz)
            o = fmaf(wz[z], po[(size_t)(idx4 + z) * DD + tid], o);
    }
    out[(size_t)(b*QQ + q) * DD + tid] = o * inv;
}

extern "C" void kernel_launch(void* const* d_in, const int* in_sizes, int n_in,
                              void* d_out, int out_size, void* d_ws, size_t ws_size,
                              hipStream_t stream) {
    (void)in_sizes; (void)n_in; (void)out_size; (void)ws_size;
    const float* querys     = (const float*)d_in[0];
    const float* keys       = (const float*)d_in[1];
    const float* values     = (const float*)d_in[2];
    const int*   valid_lens = (const int*)d_in[3];
    const float* Wq         = (const float*)d_in[4];
    const float* Wk         = (const float*)d_in[5];
    const float* w_v        = (const float*)d_in[6];
    float* out = (float*)d_out;

    float*  qf    = (float*)d_ws;                          // 1 MB f32 (pre-scaled)
    ushort* kfeat = (ushort*)(qf + (size_t)BB*QQ*HH);      // 4 MB bf16 (pre-scaled)
    float*  pm    = (float*)(kfeat + (size_t)BB*KK*HH);    // 16 KB
    float*  pl    = pm + BB*QQ*NZ;                         // 16 KB
    float*  po    = pl + BB*QQ*NZ;                         // 4 MB

    proj_both<<<dim3(16 + BB*KK/64, HH/64), 256, 0, stream>>>(
        querys, Wq, qf, keys, Wk, kfeat, valid_lens);
    fused_flash<<<dim3(PERSIST), 256, 0, stream>>>(
        qf, kfeat, w_v, valid_lens, values, pm, pl, po);
    combine_kernel<<<dim3(BB, QQ), 256, 0, stream>>>(
        pm, pl, po, valid_lens, out);
}